// Round 1
// baseline (269.680 us; speedup 1.0000x reference)
//
#include <hip/hip_runtime.h>

#define BB 8        // batches per block
#define SS 30
#define DD 4
#define QQ 16
#define NV1 21
#define NV2 11
#define NVT 32      // NV1 + NV2
#define THREADS 256

__device__ __forceinline__ float fast_tanh(float x) {
    // tanh(x) = 1 - 2/(exp(2x)+1); saturates correctly at +-1 for large |x|
    float e = __expf(2.0f * x);
    return 1.0f - 2.0f / (e + 1.0f);
}

__global__ __launch_bounds__(THREADS) void fused_dual_attn(
    const float* __restrict__ x,
    const float* __restrict__ q1w, const float* __restrict__ q1b,
    const float* __restrict__ k1w, const float* __restrict__ k1b,
    const float* __restrict__ v1w, const float* __restrict__ v1b,
    const float* __restrict__ q2w, const float* __restrict__ q2b,
    const float* __restrict__ k2w, const float* __restrict__ k2b,
    const float* __restrict__ v2w, const float* __restrict__ v2b,
    float* __restrict__ out1, float* __restrict__ out2)
{
    __shared__ float xs[BB * SS * DD];       // 960 floats
    __shared__ float cm[2][20];              // per branch: M[16] (d*4+e), w[4]
    __shared__ float vwl[DD][NVT];           // fused V weights [d][o]
    __shared__ float vbl[NVT];               // fused V bias
    __shared__ float o1s[BB * SS * NV1];     // 5040 floats
    __shared__ float o2s[BB * SS * NV2];     // 2640 floats

    const int tid = threadIdx.x;
    const long long blk = blockIdx.x;

    // ---- per-block weight-derived constants ----
    if (tid < 40) {
        const int br = tid / 20, idx = tid % 20;
        const float* qw = br ? q2w : q1w;
        const float* qb = br ? q2b : q1b;
        const float* kw = br ? k2w : k1w;
        float acc = 0.f;
        if (idx < 16) {
            const int d = idx >> 2, e = idx & 3;
            #pragma unroll
            for (int q = 0; q < QQ; ++q) acc += qw[d * QQ + q] * kw[e * QQ + q];
        } else {
            const int e = idx - 16;
            #pragma unroll
            for (int q = 0; q < QQ; ++q) acc += kw[e * QQ + q] * qb[q];
        }
        cm[br][idx] = acc;
    }
    if (tid >= 64 && tid < 64 + DD * NVT) {
        const int i = tid - 64;
        const int d = i >> 5, o = i & 31;
        vwl[d][o] = (o < NV1) ? v1w[d * NV1 + o] : v2w[d * NV2 + (o - NV1)];
    }
    if (tid >= 192 && tid < 192 + NVT) {
        const int o = tid - 192;
        vbl[o] = (o < NV1) ? v1b[o] : v2b[o - NV1];
    }

    // ---- stage x for BB batches (coalesced float4) ----
    {
        const float4* xg = reinterpret_cast<const float4*>(x + blk * (BB * SS * DD));
        if (tid < (BB * SS * DD) / 4) {
            reinterpret_cast<float4*>(xs)[tid] = xg[tid];
        }
    }
    __syncthreads();

    // ---- compute: one thread per (batch, row s) ----
    if (tid < BB * SS) {
        const int b = tid / SS;
        const int s = tid - b * SS;
        const float4* xb = reinterpret_cast<const float4*>(xs) + b * SS;
        const float4 xv = xb[s];

        float g1[4], g2[4];
        #pragma unroll
        for (int e = 0; e < 4; ++e) {
            g1[e] = cm[0][16 + e] + xv.x * cm[0][e] + xv.y * cm[0][4 + e]
                  + xv.z * cm[0][8 + e] + xv.w * cm[0][12 + e];
            g2[e] = cm[1][16 + e] + xv.x * cm[1][e] + xv.y * cm[1][4 + e]
                  + xv.z * cm[1][8 + e] + xv.w * cm[1][12 + e];
        }

        // pass A: row max
        float m1 = -INFINITY, m2 = -INFINITY;
        #pragma unroll
        for (int t = 0; t < SS; ++t) {
            const float4 xt = xb[t];
            const float s1 = g1[0] * xt.x + g1[1] * xt.y + g1[2] * xt.z + g1[3] * xt.w;
            const float s2 = g2[0] * xt.x + g2[1] * xt.y + g2[2] * xt.z + g2[3] * xt.w;
            m1 = fmaxf(m1, s1);
            m2 = fmaxf(m2, s2);
        }

        // pass B: exp-accumulate h = sum_t p_t * x_t and sums
        float sum1 = 0.f, sum2 = 0.f;
        float h1[4] = {0.f, 0.f, 0.f, 0.f}, h2[4] = {0.f, 0.f, 0.f, 0.f};
        #pragma unroll
        for (int t = 0; t < SS; ++t) {
            const float4 xt = xb[t];
            const float s1 = g1[0] * xt.x + g1[1] * xt.y + g1[2] * xt.z + g1[3] * xt.w;
            const float s2 = g2[0] * xt.x + g2[1] * xt.y + g2[2] * xt.z + g2[3] * xt.w;
            const float p1 = __expf(s1 - m1);
            const float p2 = __expf(s2 - m2);
            sum1 += p1; sum2 += p2;
            h1[0] += p1 * xt.x; h1[1] += p1 * xt.y; h1[2] += p1 * xt.z; h1[3] += p1 * xt.w;
            h2[0] += p2 * xt.x; h2[1] += p2 * xt.y; h2[2] += p2 * xt.z; h2[3] += p2 * xt.w;
        }
        const float inv1 = 1.f / sum1, inv2 = 1.f / sum2;
        #pragma unroll
        for (int e = 0; e < 4; ++e) { h1[e] *= inv1; h2[e] *= inv2; }

        // epilogue: project through V weights + tanh, stage in LDS
        float* o1p = o1s + (b * SS + s) * NV1;
        #pragma unroll
        for (int o = 0; o < NV1; ++o) {
            const float v = vbl[o] + h1[0] * vwl[0][o] + h1[1] * vwl[1][o]
                          + h1[2] * vwl[2][o] + h1[3] * vwl[3][o];
            o1p[o] = fast_tanh(v);
        }
        float* o2p = o2s + (b * SS + s) * NV2;
        #pragma unroll
        for (int o = 0; o < NV2; ++o) {
            const float v = vbl[NV1 + o] + h2[0] * vwl[0][NV1 + o] + h2[1] * vwl[1][NV1 + o]
                          + h2[2] * vwl[2][NV1 + o] + h2[3] * vwl[3][NV1 + o];
            o2p[o] = fast_tanh(v);
        }
    }
    __syncthreads();

    // ---- coalesced float4 writes from LDS staging ----
    {
        const int n1 = (BB * SS * NV1) / 4;  // 1260
        float4* dst1 = reinterpret_cast<float4*>(out1 + blk * (BB * SS * NV1));
        const float4* src1 = reinterpret_cast<const float4*>(o1s);
        for (int i = tid; i < n1; i += THREADS) dst1[i] = src1[i];

        const int n2 = (BB * SS * NV2) / 4;  // 660
        float4* dst2 = reinterpret_cast<float4*>(out2 + blk * (BB * SS * NV2));
        const float4* src2 = reinterpret_cast<const float4*>(o2s);
        for (int i = tid; i < n2; i += THREADS) dst2[i] = src2[i];
    }
}

extern "C" void kernel_launch(void* const* d_in, const int* in_sizes, int n_in,
                              void* d_out, int out_size, void* d_ws, size_t ws_size,
                              hipStream_t stream) {
    const float* x   = (const float*)d_in[0];
    const float* q1w = (const float*)d_in[1];
    const float* q1b = (const float*)d_in[2];
    const float* k1w = (const float*)d_in[3];
    const float* k1b = (const float*)d_in[4];
    const float* v1w = (const float*)d_in[5];
    const float* v1b = (const float*)d_in[6];
    const float* q2w = (const float*)d_in[7];
    const float* q2b = (const float*)d_in[8];
    const float* k2w = (const float*)d_in[9];
    const float* k2b = (const float*)d_in[10];
    const float* v2w = (const float*)d_in[11];
    const float* v2b = (const float*)d_in[12];

    const long long B = 131072LL;
    float* out1 = (float*)d_out;
    float* out2 = out1 + B * SS * NV1;

    const int nblocks = (int)(B / BB);  // 16384
    fused_dual_attn<<<nblocks, THREADS, 0, stream>>>(
        x, q1w, q1b, k1w, k1b, v1w, v1b,
        q2w, q2b, k2w, k2b, v2w, v2b, out1, out2);
}

// Round 2
// 181.448 us; speedup vs baseline: 1.4863x; 1.4863x over previous
//
#include <hip/hip_runtime.h>

#define BB 8        // batches per block
#define SS 30
#define DD 4
#define QQ 16
#define NV1 21
#define NV2 11
#define NVT 32      // NV1 + NV2
#define THREADS 256
#define ROWS (BB * SS)   // 240 rows per block

__device__ __forceinline__ float fast_tanh(float x) {
    // tanh(x) = 1 - 2/(exp(2x)+1)
    float e = __expf(2.0f * x);
    float r = __builtin_amdgcn_rcpf(e + 1.0f);
    return fmaf(-2.0f, r, 1.0f);
}

__global__ __launch_bounds__(THREADS, 6) void fused_dual_attn(
    const float* __restrict__ x,
    const float* __restrict__ q1w, const float* __restrict__ q1b,
    const float* __restrict__ k1w, const float* __restrict__ k1b,
    const float* __restrict__ v1w, const float* __restrict__ v1b,
    const float* __restrict__ q2w, const float* __restrict__ q2b,
    const float* __restrict__ k2w, const float* __restrict__ k2b,
    const float* __restrict__ v2w, const float* __restrict__ v2b,
    float* __restrict__ out1, float* __restrict__ out2)
{
    __shared__ float4 xsv[ROWS];         // staged x rows        (3.84 KB)
    __shared__ float  cm[2][20];         // per branch: M[16], w[4]
    __shared__ float4 vwt[NVT];          // V weights, float4 per output col
    __shared__ float  vbl[NVT];          // V bias
    __shared__ float4 h1s[ROWS];         // normalized attention context, br1
    __shared__ float4 h2s[ROWS];         // br2

    const int tid = threadIdx.x;
    const long long blk = blockIdx.x;

    // ---- per-block weight-derived constants ----
    if (tid < 40) {
        const int br = tid / 20, idx = tid % 20;
        const float* qw = br ? q2w : q1w;
        const float* qb = br ? q2b : q1b;
        const float* kw = br ? k2w : k1w;
        float acc = 0.f;
        if (idx < 16) {
            const int d = idx >> 2, e = idx & 3;
            #pragma unroll
            for (int q = 0; q < QQ; ++q) acc += qw[d * QQ + q] * kw[e * QQ + q];
        } else {
            const int e = idx - 16;
            #pragma unroll
            for (int q = 0; q < QQ; ++q) acc += kw[e * QQ + q] * qb[q];
        }
        cm[br][idx] = acc;
    }
    if (tid >= 64 && tid < 64 + NVT) {
        const int o = tid - 64;
        if (o < NV1) {
            vwt[o] = make_float4(v1w[o], v1w[NV1 + o], v1w[2 * NV1 + o], v1w[3 * NV1 + o]);
            vbl[o] = v1b[o];
        } else {
            const int p = o - NV1;
            vwt[o] = make_float4(v2w[p], v2w[NV2 + p], v2w[2 * NV2 + p], v2w[3 * NV2 + p]);
            vbl[o] = v2b[p];
        }
    }

    // ---- stage x for BB batches (coalesced float4) ----
    {
        const float4* xg = reinterpret_cast<const float4*>(x) + blk * ROWS;
        if (tid < ROWS) xsv[tid] = xg[tid];
    }
    __syncthreads();

    // ---- compute: one thread per row; single-pass softmax (no max needed) ----
    if (tid < ROWS) {
        const int b = (unsigned)tid / SS;
        const float4* xb = xsv + b * SS;
        const float4 xv = xsv[tid];

        float g1[4], g2[4];
        #pragma unroll
        for (int e = 0; e < 4; ++e) {
            g1[e] = cm[0][16 + e] + xv.x * cm[0][e] + xv.y * cm[0][4 + e]
                  + xv.z * cm[0][8 + e] + xv.w * cm[0][12 + e];
            g2[e] = cm[1][16 + e] + xv.x * cm[1][e] + xv.y * cm[1][4 + e]
                  + xv.z * cm[1][8 + e] + xv.w * cm[1][12 + e];
        }

        float sum1 = 0.f, sum2 = 0.f;
        float h1[4] = {0.f, 0.f, 0.f, 0.f}, h2[4] = {0.f, 0.f, 0.f, 0.f};
        #pragma unroll
        for (int t = 0; t < SS; ++t) {
            const float4 xt = xb[t];
            const float s1 = fmaf(g1[0], xt.x, fmaf(g1[1], xt.y, fmaf(g1[2], xt.z, g1[3] * xt.w)));
            const float s2 = fmaf(g2[0], xt.x, fmaf(g2[1], xt.y, fmaf(g2[2], xt.z, g2[3] * xt.w)));
            const float p1 = __expf(s1);   // no max subtraction: |s| << 88
            const float p2 = __expf(s2);
            sum1 += p1; sum2 += p2;
            h1[0] = fmaf(p1, xt.x, h1[0]); h1[1] = fmaf(p1, xt.y, h1[1]);
            h1[2] = fmaf(p1, xt.z, h1[2]); h1[3] = fmaf(p1, xt.w, h1[3]);
            h2[0] = fmaf(p2, xt.x, h2[0]); h2[1] = fmaf(p2, xt.y, h2[1]);
            h2[2] = fmaf(p2, xt.z, h2[2]); h2[3] = fmaf(p2, xt.w, h2[3]);
        }
        const float inv1 = __builtin_amdgcn_rcpf(sum1);
        const float inv2 = __builtin_amdgcn_rcpf(sum2);
        h1s[tid] = make_float4(h1[0] * inv1, h1[1] * inv1, h1[2] * inv1, h1[3] * inv1);
        h2s[tid] = make_float4(h2[0] * inv2, h2[1] * inv2, h2[2] * inv2, h2[3] * inv2);
    }
    __syncthreads();

    // ---- write phase: V-projection + tanh fused into coalesced float4 stores ----
    {
        float4* dst1 = reinterpret_cast<float4*>(out1) + blk * (ROWS * NV1 / 4);
        const int n1 = ROWS * NV1 / 4;   // 1260
        for (int i = tid; i < n1; i += THREADS) {
            const int e0 = i * 4;
            float res[4];
            #pragma unroll
            for (int j = 0; j < 4; ++j) {
                const unsigned e = e0 + j;
                const unsigned r = e / NV1;
                const unsigned o = e - r * NV1;
                const float4 h = h1s[r];
                const float4 w = vwt[o];
                const float v = vbl[o] + fmaf(h.x, w.x, fmaf(h.y, w.y, fmaf(h.z, w.z, h.w * w.w)));
                res[j] = fast_tanh(v);
            }
            dst1[i] = make_float4(res[0], res[1], res[2], res[3]);
        }

        float4* dst2 = reinterpret_cast<float4*>(out2) + blk * (ROWS * NV2 / 4);
        const int n2 = ROWS * NV2 / 4;   // 660
        for (int i = tid; i < n2; i += THREADS) {
            const int e0 = i * 4;
            float res[4];
            #pragma unroll
            for (int j = 0; j < 4; ++j) {
                const unsigned e = e0 + j;
                const unsigned r = e / NV2;
                const unsigned o = e - r * NV2;
                const float4 h = h2s[r];
                const float4 w = vwt[NV1 + o];
                const float v = vbl[NV1 + o] + fmaf(h.x, w.x, fmaf(h.y, w.y, fmaf(h.z, w.z, h.w * w.w)));
                res[j] = fast_tanh(v);
            }
            dst2[i] = make_float4(res[0], res[1], res[2], res[3]);
        }
    }
}

extern "C" void kernel_launch(void* const* d_in, const int* in_sizes, int n_in,
                              void* d_out, int out_size, void* d_ws, size_t ws_size,
                              hipStream_t stream) {
    const float* x   = (const float*)d_in[0];
    const float* q1w = (const float*)d_in[1];
    const float* q1b = (const float*)d_in[2];
    const float* k1w = (const float*)d_in[3];
    const float* k1b = (const float*)d_in[4];
    const float* v1w = (const float*)d_in[5];
    const float* v1b = (const float*)d_in[6];
    const float* q2w = (const float*)d_in[7];
    const float* q2b = (const float*)d_in[8];
    const float* k2w = (const float*)d_in[9];
    const float* k2b = (const float*)d_in[10];
    const float* v2w = (const float*)d_in[11];
    const float* v2b = (const float*)d_in[12];

    const long long B = 131072LL;
    float* out1 = (float*)d_out;
    float* out2 = out1 + B * SS * NV1;

    const int nblocks = (int)(B / BB);  // 16384
    fused_dual_attn<<<nblocks, THREADS, 0, stream>>>(
        x, q1w, q1b, k1w, k1b, v1w, v1b,
        q2w, q2b, k2w, k2b, v2w, v2b, out1, out2);
}

// Round 4
// 165.200 us; speedup vs baseline: 1.6325x; 1.0984x over previous
//
#include <hip/hip_runtime.h>

#define SS 30
#define QQ 16
#define NV1 21
#define NV2 11
#define NVT 32
#define NB 16                  // batches per block
#define ROWS (NB * SS)         // 480
#define CT (NB * (SS / 2))     // 240 compute threads (2 rows each)
#define THREADS 256

#define LOG2E 1.44269504088896340736f

typedef float v2f __attribute__((ext_vector_type(2)));

__device__ __forceinline__ v2f bcast(float x) { v2f r; r.x = x; r.y = x; return r; }
__device__ __forceinline__ v2f pkfma(v2f a, v2f b, v2f c) {
    return __builtin_elementwise_fma(a, b, c);   // -> v_pk_fma_f32 on gfx950
}

__global__ __launch_bounds__(THREADS, 6) void fused_dual_attn(
    const float* __restrict__ x,
    const float* __restrict__ q1w, const float* __restrict__ q1b,
    const float* __restrict__ k1w, const float* __restrict__ k1b,
    const float* __restrict__ v1w, const float* __restrict__ v1b,
    const float* __restrict__ q2w, const float* __restrict__ q2b,
    const float* __restrict__ k2w, const float* __restrict__ k2b,
    const float* __restrict__ v2w, const float* __restrict__ v2b,
    float* __restrict__ out1, float* __restrict__ out2)
{
    __shared__ float4 xsv[ROWS];     // 7.68 KB staged x
    __shared__ float  cm[2][20];     // per branch: log2e*(M[16], w[4])
    __shared__ float4 vwt[NVT];      // V weights * 2*log2e, float4 over d
    __shared__ float  vbl[NVT];      // V bias * 2*log2e
    __shared__ float4 h1s[ROWS];     // normalized context, branch 1
    __shared__ float4 h2s[ROWS];     // branch 2

    const int tid = threadIdx.x;
    const long long blk = blockIdx.x;

    // ---- per-block weight-derived constants (scaled by log2e) ----
    if (tid < 40) {
        const int br = tid / 20, idx = tid % 20;
        const float* qw = br ? q2w : q1w;
        const float* qb = br ? q2b : q1b;
        const float* kw = br ? k2w : k1w;
        float acc = 0.f;
        if (idx < 16) {
            const int d = idx >> 2, e = idx & 3;
            #pragma unroll
            for (int q = 0; q < QQ; ++q) acc += qw[d * QQ + q] * kw[e * QQ + q];
        } else {
            const int e = idx - 16;
            #pragma unroll
            for (int q = 0; q < QQ; ++q) acc += kw[e * QQ + q] * qb[q];
        }
        cm[br][idx] = acc * LOG2E;
    }
    if (tid >= 64 && tid < 64 + NVT) {
        const int o = tid - 64;
        const float s2l = 2.0f * LOG2E;
        if (o < NV1) {
            vwt[o] = make_float4(v1w[o] * s2l, v1w[NV1 + o] * s2l,
                                 v1w[2 * NV1 + o] * s2l, v1w[3 * NV1 + o] * s2l);
            vbl[o] = v1b[o] * s2l;
        } else {
            const int p = o - NV1;
            vwt[o] = make_float4(v2w[p] * s2l, v2w[NV2 + p] * s2l,
                                 v2w[2 * NV2 + p] * s2l, v2w[3 * NV2 + p] * s2l);
            vbl[o] = v2b[p] * s2l;
        }
    }

    // ---- stage x (coalesced float4) ----
    {
        const float4* xg = reinterpret_cast<const float4*>(x) + blk * ROWS;
        for (int i = tid; i < ROWS; i += THREADS) xsv[i] = xg[i];
    }
    __syncthreads();

    // ---- compute: 2 rows per thread, packed-f32 main loop ----
    if (tid < CT) {
        const int batch = (unsigned)tid / 15;
        const int sA = tid - batch * 15;
        const int rowA = batch * SS + sA;
        const int rowB = rowA + 15;
        const float4* xb = xsv + batch * SS;
        const float4 xA = xsv[rowA];
        const float4 xB = xsv[rowB];

        // g vectors for both rows, packed (row A in lo, row B in hi)
        v2f g1p[4], g2p[4];
        #pragma unroll
        for (int e = 0; e < 4; ++e) {
            const float a1 = cm[0][16 + e] + xA.x * cm[0][e] + xA.y * cm[0][4 + e]
                           + xA.z * cm[0][8 + e] + xA.w * cm[0][12 + e];
            const float b1 = cm[0][16 + e] + xB.x * cm[0][e] + xB.y * cm[0][4 + e]
                           + xB.z * cm[0][8 + e] + xB.w * cm[0][12 + e];
            g1p[e].x = a1; g1p[e].y = b1;
            const float a2 = cm[1][16 + e] + xA.x * cm[1][e] + xA.y * cm[1][4 + e]
                           + xA.z * cm[1][8 + e] + xA.w * cm[1][12 + e];
            const float b2 = cm[1][16 + e] + xB.x * cm[1][e] + xB.y * cm[1][4 + e]
                           + xB.z * cm[1][8 + e] + xB.w * cm[1][12 + e];
            g2p[e].x = a2; g2p[e].y = b2;
        }

        v2f sum1 = {0.f, 0.f}, sum2 = {0.f, 0.f};
        v2f h1p[4], h2p[4];
        #pragma unroll
        for (int e = 0; e < 4; ++e) { h1p[e] = sum1; h2p[e] = sum1; }

        #pragma unroll
        for (int t = 0; t < SS; ++t) {
            const float4 xt = xb[t];
            const v2f bx = bcast(xt.x), by = bcast(xt.y), bz = bcast(xt.z), bw = bcast(xt.w);
            v2f s1 = g1p[3] * bw;
            s1 = pkfma(g1p[2], bz, s1);
            s1 = pkfma(g1p[1], by, s1);
            s1 = pkfma(g1p[0], bx, s1);
            v2f s2 = g2p[3] * bw;
            s2 = pkfma(g2p[2], bz, s2);
            s2 = pkfma(g2p[1], by, s2);
            s2 = pkfma(g2p[0], bx, s2);
            v2f p1, p2;
            p1.x = __builtin_amdgcn_exp2f(s1.x);
            p1.y = __builtin_amdgcn_exp2f(s1.y);
            p2.x = __builtin_amdgcn_exp2f(s2.x);
            p2.y = __builtin_amdgcn_exp2f(s2.y);
            sum1 = sum1 + p1;
            sum2 = sum2 + p2;
            h1p[0] = pkfma(p1, bx, h1p[0]);
            h1p[1] = pkfma(p1, by, h1p[1]);
            h1p[2] = pkfma(p1, bz, h1p[2]);
            h1p[3] = pkfma(p1, bw, h1p[3]);
            h2p[0] = pkfma(p2, bx, h2p[0]);
            h2p[1] = pkfma(p2, by, h2p[1]);
            h2p[2] = pkfma(p2, bz, h2p[2]);
            h2p[3] = pkfma(p2, bw, h2p[3]);
        }
        const float i1A = __builtin_amdgcn_rcpf(sum1.x);
        const float i1B = __builtin_amdgcn_rcpf(sum1.y);
        const float i2A = __builtin_amdgcn_rcpf(sum2.x);
        const float i2B = __builtin_amdgcn_rcpf(sum2.y);
        h1s[rowA] = make_float4(h1p[0].x * i1A, h1p[1].x * i1A, h1p[2].x * i1A, h1p[3].x * i1A);
        h1s[rowB] = make_float4(h1p[0].y * i1B, h1p[1].y * i1B, h1p[2].y * i1B, h1p[3].y * i1B);
        h2s[rowA] = make_float4(h2p[0].x * i2A, h2p[1].x * i2A, h2p[2].x * i2A, h2p[3].x * i2A);
        h2s[rowB] = make_float4(h2p[0].y * i2B, h2p[1].y * i2B, h2p[2].y * i2B, h2p[3].y * i2B);
    }
    __syncthreads();

    // ---- write phase: V-projection + tanh fused into coalesced float4 stores ----
    {
        const int n1 = ROWS * NV1 / 4;   // 2520
        float4* dst1 = reinterpret_cast<float4*>(out1) + blk * n1;
        for (int i = tid; i < n1; i += THREADS) {
            const int e0 = i * 4;
            float res[4];
            #pragma unroll
            for (int j = 0; j < 4; ++j) {
                const unsigned e = e0 + j;
                const unsigned r = e / NV1;
                const unsigned o = e - r * NV1;
                const float4 h = h1s[r];
                const float4 w = vwt[o];
                const float v = vbl[o] + fmaf(h.x, w.x, fmaf(h.y, w.y, fmaf(h.z, w.z, h.w * w.w)));
                const float ex = __builtin_amdgcn_exp2f(v);       // exp(2*orig) via folded scale
                const float rr = __builtin_amdgcn_rcpf(ex + 1.0f);
                res[j] = fmaf(-2.0f, rr, 1.0f);                   // tanh
            }
            dst1[i] = make_float4(res[0], res[1], res[2], res[3]);
        }

        const int n2 = ROWS * NV2 / 4;   // 1320
        float4* dst2 = reinterpret_cast<float4*>(out2) + blk * n2;
        for (int i = tid; i < n2; i += THREADS) {
            const int e0 = i * 4;
            float res[4];
            #pragma unroll
            for (int j = 0; j < 4; ++j) {
                const unsigned e = e0 + j;
                const unsigned r = e / NV2;
                const unsigned o = e - r * NV2;
                const float4 h = h2s[r];
                const float4 w = vwt[NV1 + o];
                const float v = vbl[NV1 + o] + fmaf(h.x, w.x, fmaf(h.y, w.y, fmaf(h.z, w.z, h.w * w.w)));
                const float ex = __builtin_amdgcn_exp2f(v);
                const float rr = __builtin_amdgcn_rcpf(ex + 1.0f);
                res[j] = fmaf(-2.0f, rr, 1.0f);
            }
            dst2[i] = make_float4(res[0], res[1], res[2], res[3]);
        }
    }
}

extern "C" void kernel_launch(void* const* d_in, const int* in_sizes, int n_in,
                              void* d_out, int out_size, void* d_ws, size_t ws_size,
                              hipStream_t stream) {
    const float* x   = (const float*)d_in[0];
    const float* q1w = (const float*)d_in[1];
    const float* q1b = (const float*)d_in[2];
    const float* k1w = (const float*)d_in[3];
    const float* k1b = (const float*)d_in[4];
    const float* v1w = (const float*)d_in[5];
    const float* v1b = (const float*)d_in[6];
    const float* q2w = (const float*)d_in[7];
    const float* q2b = (const float*)d_in[8];
    const float* k2w = (const float*)d_in[9];
    const float* k2b = (const float*)d_in[10];
    const float* v2w = (const float*)d_in[11];
    const float* v2b = (const float*)d_in[12];

    const long long B = 131072LL;
    float* out1 = (float*)d_out;
    float* out2 = out1 + B * SS * NV1;

    const int nblocks = (int)(B / NB);  // 8192
    fused_dual_attn<<<nblocks, THREADS, 0, stream>>>(
        x, q1w, q1b, k1w, k1b, v1w, v1b,
        q2w, q2b, k2w, k2b, v2w, v2b, out1, out2);
}